// Round 5
// baseline (305.934 us; speedup 1.0000x reference)
//
#include <hip/hip_runtime.h>
#include <hip/hip_bf16.h>

namespace {

constexpr int E  = 64;
constexpr int C  = 64;
constexpr int D  = 1024;
constexpr int DF = 2048;
constexpr int BK = 32;    // K per step (32 f32 = 128 B rows in LDS)

using u16    = unsigned short;
using f32x4  = __attribute__((ext_vector_type(4))) float;
using short8 = __attribute__((ext_vector_type(8))) short;

__device__ __forceinline__ u16 f2bf(float f) {
  union { __hip_bfloat16 h; u16 u; } v;
  v.h = __float2bfloat16(f);  // RNE; compiler emits HW cvt
  return v.u;
}

__device__ __forceinline__ short8 cvt8(const f32x4& lo, const f32x4& hi) {
  short8 r;
#pragma unroll
  for (int i = 0; i < 4; ++i) {
    r[i]     = (short)f2bf(lo[i]);
    r[4 + i] = (short)f2bf(hi[i]);
  }
  return r;
}

// async 16B global -> LDS (linear dest: wave-uniform base + lane*16)
__device__ __forceinline__ void gl_lds16(const void* g, void* l) {
  __builtin_amdgcn_global_load_lds(
      (const __attribute__((address_space(1))) unsigned*)g,
      (__attribute__((address_space(3))) unsigned*)l, 16, 0, 0);
}

// read one bf16 fragment (8 f32 -> short8) from a 128B-row fp32 LDS region,
// XOR-swizzled: 16B-granule ^ (row & 7)  (matches the pre-swizzled source)
__device__ __forceinline__ short8 rd_frag_f32(const char* region, int r, int q) {
  const int s  = (r & 7) << 4;
  const int b0 = r * 128 + ((q * 32) ^ s);
  const int b1 = r * 128 + ((q * 32 + 16) ^ s);
  f32x4 lo = *reinterpret_cast<const f32x4*>(region + b0);
  f32x4 hi = *reinterpret_cast<const f32x4*>(region + b1);
  return cvt8(lo, hi);
}

// ---------------- Stage 1: H = silu(X*Wg^T) * (X*Wu^T), bf16 out -----------
// BN=64, 3-buffer ring, ONE barrier per K-step.
__global__ __launch_bounds__(256, 2) void ffn_stage1(
    const float* __restrict__ X, const float* __restrict__ Wg,
    const float* __restrict__ Wu, u16* __restrict__ H) {
  const int b   = blockIdx.x;          // 0..2047
  const int xcd = b & 7;
  const int j   = b >> 3;              // 0..255
  const int e   = xcd + 8 * (j >> 5);  // all 32 tiles of expert e on one XCD
  const int n0  = (j & 31) * 64;

  const int tid  = threadIdx.x;
  const int lane = tid & 63;
  const int wv   = tid >> 6;
  const int rl   = lane & 15;
  const int q    = lane >> 4;

  // per buffer: X 8KB | Wg 8KB | Wu 8KB = 24KB; x3 = 72KB -> 2 blocks/CU
  __shared__ __align__(16) char lds[3][24576];
  constexpr int OX = 0, OG = 8192, OU = 16384;

  const float* xbase = X  + (size_t)(e * C) * D;
  const float* gbase = Wg + ((size_t)e * DF + n0) * D;
  const float* ubase = Wu + ((size_t)e * DF + n0) * D;

  // one K-tile: exactly 6 global_load_lds per wave (vmcnt bookkeeping!)
  auto STAGE = [&](char* lb, int kt) {
#pragma unroll
    for (int i = 0; i < 2; ++i) {
      const int o   = tid + i * 256;      // 16B-granule index, 512 per region
      const int row = o >> 3;             // 64 rows x 128B
      const int gc  = (o & 7) ^ (row & 7);
      const size_t goff = (size_t)row * D + (size_t)kt * BK + gc * 4;
      gl_lds16(xbase + goff, lb + OX + o * 16);
      gl_lds16(gbase + goff, lb + OG + o * 16);
      gl_lds16(ubase + goff, lb + OU + o * 16);
    }
  };

  const f32x4 zero = {0.f, 0.f, 0.f, 0.f};
  f32x4 accg[4], accu[4];
#pragma unroll
  for (int mf = 0; mf < 4; ++mf) { accg[mf] = zero; accu[mf] = zero; }

  const int wr = wv * 16 + rl;  // this wave's W row (0..63)

  auto COMPUTE = [&](const char* lb) {
    short8 a[4];
#pragma unroll
    for (int mf = 0; mf < 4; ++mf)
      a[mf] = rd_frag_f32(lb + OX, mf * 16 + rl, q);
    short8 g = rd_frag_f32(lb + OG, wr, q);
    short8 u = rd_frag_f32(lb + OU, wr, q);
#pragma unroll
    for (int mf = 0; mf < 4; ++mf) {
      accg[mf] = __builtin_amdgcn_mfma_f32_16x16x32_bf16(a[mf], g, accg[mf], 0, 0, 0);
      accu[mf] = __builtin_amdgcn_mfma_f32_16x16x32_bf16(a[mf], u, accu[mf], 0, 0, 0);
    }
  };

  constexpr int NK = D / BK;  // 32
  STAGE(lds[0], 0);
  STAGE(lds[1], 1);                     // 12 outstanding
  asm volatile("s_waitcnt vmcnt(6)" ::: "memory");  // tile 0 resident
  __builtin_amdgcn_s_barrier();
  __builtin_amdgcn_sched_barrier(0);

  for (int kt = 0; kt < NK - 1; ++kt) {
    COMPUTE(lds[kt % 3]);
    if (kt + 2 < NK) {
      STAGE(lds[(kt + 2) % 3], kt + 2);  // overwrites buffer read at kt-1
      asm volatile("s_waitcnt vmcnt(6)" ::: "memory");  // tile kt+1 resident
    } else {
      asm volatile("s_waitcnt vmcnt(0)" ::: "memory");
    }
    __builtin_amdgcn_s_barrier();
    __builtin_amdgcn_sched_barrier(0);
  }
  COMPUTE(lds[(NK - 1) % 3]);

  // epilogue: silu(g)*u -> bf16. C/D layout: col=lane&15, row=(lane>>4)*4+reg
#pragma unroll
  for (int mf = 0; mf < 4; ++mf)
#pragma unroll
    for (int r = 0; r < 4; ++r) {
      float gv = accg[mf][r];
      float uv = accu[mf][r];
      float h  = (gv / (1.f + __expf(-gv))) * uv;
      int c = mf * 16 + (lane >> 4) * 4 + r;
      int f = n0 + wr;
      H[((size_t)(e * C) + c) * DF + f] = f2bf(h);
    }
}

// ---------------- Stage 2: out = H * Wd^T (fp32 out) -----------------------
// BN=128, 3-buffer ring, ONE barrier per K-step.
__global__ __launch_bounds__(256, 2) void ffn_stage2(
    const u16* __restrict__ H, const float* __restrict__ Wd,
    float* __restrict__ out) {
  const int b   = blockIdx.x;          // 0..511
  const int xcd = b & 7;
  const int j   = b >> 3;              // 0..63
  const int e   = xcd + 8 * (j >> 3);  // same XCD that produced H[e]
  const int n0  = (j & 7) * 128;

  const int tid  = threadIdx.x;
  const int lane = tid & 63;
  const int wv   = tid >> 6;
  const int rl   = lane & 15;
  const int q    = lane >> 4;

  // per buffer: H 4KB | Wd 16KB = 20KB; x3 = 60KB -> 2 blocks/CU
  __shared__ __align__(16) char lds[3][20480];
  constexpr int OH = 0, OW = 4096;

  const u16*   hbase = H  + (size_t)(e * C) * DF;
  const float* wbase = Wd + ((size_t)e * D + n0) * DF;

  // one K-tile: exactly 5 global_load_lds per wave
  auto STAGE = [&](char* lb, int kt) {
    {  // H: 64 rows x 64B (32 bf16), swz granule ^ ((row>>1)&3)
      const int row = tid >> 2;
      const int gc  = (tid & 3) ^ ((row >> 1) & 3);
      gl_lds16(hbase + (size_t)row * DF + (size_t)kt * BK + gc * 8, lb + OH + tid * 16);
    }
#pragma unroll
    for (int i = 0; i < 4; ++i) {  // Wd: 128 rows x 128B
      const int o   = tid + i * 256;
      const int row = o >> 3;
      const int gc  = (o & 7) ^ (row & 7);
      gl_lds16(wbase + (size_t)row * DF + (size_t)kt * BK + gc * 4, lb + OW + o * 16);
    }
  };

  const f32x4 zero = {0.f, 0.f, 0.f, 0.f};
  f32x4 acc[4][2];
#pragma unroll
  for (int mf = 0; mf < 4; ++mf)
#pragma unroll
    for (int nf = 0; nf < 2; ++nf) acc[mf][nf] = zero;

  auto COMPUTE = [&](const char* lb) {
    short8 a[4], bfr[2];
#pragma unroll
    for (int mf = 0; mf < 4; ++mf) {  // bf16 H frags, swizzled read
      const int r  = mf * 16 + rl;
      const int gp = q ^ ((r >> 1) & 3);
      a[mf] = *reinterpret_cast<const short8*>(lb + OH + r * 64 + gp * 16);
    }
#pragma unroll
    for (int nf = 0; nf < 2; ++nf)
      bfr[nf] = rd_frag_f32(lb + OW, wv * 32 + nf * 16 + rl, q);
#pragma unroll
    for (int mf = 0; mf < 4; ++mf)
#pragma unroll
      for (int nf = 0; nf < 2; ++nf)
        acc[mf][nf] = __builtin_amdgcn_mfma_f32_16x16x32_bf16(a[mf], bfr[nf], acc[mf][nf], 0, 0, 0);
  };

  constexpr int NK = DF / BK;  // 64
  STAGE(lds[0], 0);
  STAGE(lds[1], 1);                     // 10 outstanding
  asm volatile("s_waitcnt vmcnt(5)" ::: "memory");
  __builtin_amdgcn_s_barrier();
  __builtin_amdgcn_sched_barrier(0);

  for (int kt = 0; kt < NK - 1; ++kt) {
    COMPUTE(lds[kt % 3]);
    if (kt + 2 < NK) {
      STAGE(lds[(kt + 2) % 3], kt + 2);
      asm volatile("s_waitcnt vmcnt(5)" ::: "memory");
    } else {
      asm volatile("s_waitcnt vmcnt(0)" ::: "memory");
    }
    __builtin_amdgcn_s_barrier();
    __builtin_amdgcn_sched_barrier(0);
  }
  COMPUTE(lds[(NK - 1) % 3]);

#pragma unroll
  for (int mf = 0; mf < 4; ++mf)
#pragma unroll
    for (int nf = 0; nf < 2; ++nf)
#pragma unroll
      for (int r = 0; r < 4; ++r) {
        int c = mf * 16 + (lane >> 4) * 4 + r;
        int d = n0 + wv * 32 + nf * 16 + rl;
        out[((size_t)(e * C) + c) * D + d] = acc[mf][nf][r];
      }
}

}  // namespace

extern "C" void kernel_launch(void* const* d_in, const int* in_sizes, int n_in,
                              void* d_out, int out_size, void* d_ws, size_t ws_size,
                              hipStream_t stream) {
  const float* X  = (const float*)d_in[0];
  const float* Wg = (const float*)d_in[1];
  const float* Wu = (const float*)d_in[2];
  const float* Wd = (const float*)d_in[3];
  float* out = (float*)d_out;
  u16* H = (u16*)d_ws;  // E*C*DF bf16 = 16.8 MB scratch

  ffn_stage1<<<dim3(E * (DF / 64)), dim3(256), 0, stream>>>(X, Wg, Wu, H);
  ffn_stage2<<<dim3(E * (D / 128)), dim3(256), 0, stream>>>(H, Wd, out);
}